// Round 3
// baseline (295.488 us; speedup 1.0000x reference)
//
#include <hip/hip_runtime.h>
#include <hip/hip_bf16.h>

typedef __bf16 bf16x8 __attribute__((ext_vector_type(8)));
typedef __bf16 bf16x4 __attribute__((ext_vector_type(4)));
typedef float f32x4 __attribute__((ext_vector_type(4)));

#define N_ 8
#define C_ 1024
#define W_ 1024
#define H_ 16
#define D_ 64

// async global->LDS, 16B per lane; LDS dest = wave-uniform base + lane*16
typedef __attribute__((address_space(3))) void lds_void;
typedef const __attribute__((address_space(1))) void gbl_void;
static __device__ __forceinline__ void gload_lds16(const void* g, void* l) {
    __builtin_amdgcn_global_load_lds((gbl_void*)g, (lds_void*)l, 16, 0, 0);
}

// ---------------------------------------------------------------------------
// convert 3 weight matrices fp32 -> bf16. grid (512, 3), block 256.
// ---------------------------------------------------------------------------
__global__ __launch_bounds__(256)
void convert_w(const float* __restrict__ s0, const float* __restrict__ s1,
               const float* __restrict__ s2, __bf16* __restrict__ dst) {
    const float* s = blockIdx.y == 0 ? s0 : (blockIdx.y == 1 ? s1 : s2);
    __bf16* d = dst + (long)blockIdx.y * C_ * C_;
    const long i = ((long)blockIdx.x * 256 + threadIdx.x) * 8;
    f32x4 a = *(const f32x4*)(const void*)(s + i);
    f32x4 b = *(const f32x4*)(const void*)(s + i + 4);
    bf16x8 v;
    #pragma unroll
    for (int t = 0; t < 4; ++t) { v[t] = (__bf16)a[t]; v[t + 4] = (__bf16)b[t]; }
    *(bf16x8*)(void*)(d + i) = v;
}

// ---------------------------------------------------------------------------
// transpose+convert hs [n][C][W] fp32 -> Xt [n][W][C] bf16.
// grid (W/64, C/64, N), block 256; 64x64 tile via fp32 LDS.
// ---------------------------------------------------------------------------
__global__ __launch_bounds__(256)
void transpose_x(const float* __restrict__ in, __bf16* __restrict__ outp) {
    __shared__ float tile[64][68];
    const long bin  = (long)blockIdx.z * C_ * W_;
    const long bout = (long)blockIdx.z * W_ * C_;
    const int w0 = blockIdx.x * 64, c0 = blockIdx.y * 64;
    const int t = threadIdx.x;
    const int rr = t >> 4;
    const int cg = (t & 15) * 4;
    #pragma unroll
    for (int it = 0; it < 4; ++it) {
        const int cr = it * 16 + rr;
        f32x4 v = *(const f32x4*)(const void*)(in + bin + (long)(c0 + cr) * W_ + w0 + cg);
        *(f32x4*)&tile[cr][cg] = v;
    }
    __syncthreads();
    #pragma unroll
    for (int it = 0; it < 4; ++it) {
        const int wr = it * 16 + rr;
        bf16x4 o;
        #pragma unroll
        for (int u = 0; u < 4; ++u) o[u] = (__bf16)tile[cg + u][wr];
        *(bf16x4*)(void*)(outp + bout + (long)(w0 + wr) * C_ + c0 + cg) = o;
    }
}

// ---------------------------------------------------------------------------
// gemm_body<OUT_T> (validated, unchanged): D = A x B^T, K=1024, bf16.
// global_load_lds(16B) staging with XOR chunk swizzle; BK=64; 32 MFMA/iter.
// ---------------------------------------------------------------------------
template<int OUT_T>
static __device__ __forceinline__
void gemm_body(const __bf16* __restrict__ Aw, const __bf16* __restrict__ Xn,
               const float* __restrict__ bias, __bf16* __restrict__ Pn,
               const int o0, const int w0,
               __bf16* __restrict__ As, __bf16* __restrict__ Bs) {
    constexpr int BK = 64;
    const int tid = threadIdx.x;
    const int wv = tid >> 6, lane = tid & 63;
    const int l15 = lane & 15, quad = lane >> 4;
    const int wr = (wv >> 1) * 64, wc = (wv & 1) * 64;
    const int lr8 = lane >> 3;
    const int lp = lane & 7;

    f32x4 acc[4][4] = {};

    for (int k0 = 0; k0 < C_; k0 += BK) {
        #pragma unroll
        for (int j = 0; j < 4; ++j) {
            const int seg = wv * 4 + j;
            const int r = seg * 8 + lr8;
            const int q = lp ^ (r & 7);
            gload_lds16(Aw + (long)(o0 + r) * C_ + k0 + q * 8, As + seg * 512);
            gload_lds16(Xn + (long)(w0 + r) * C_ + k0 + q * 8, Bs + seg * 512);
        }
        __syncthreads();
        bf16x8 af[4][2], bf[4][2];
        #pragma unroll
        for (int mt = 0; mt < 4; ++mt) {
            const int R = wr + mt * 16 + l15;
            #pragma unroll
            for (int s = 0; s < 2; ++s) {
                const int pos = (s * 4 + quad) ^ (R & 7);
                af[mt][s] = *(const bf16x8*)(const void*)&As[R * 64 + pos * 8];
            }
        }
        #pragma unroll
        for (int nt = 0; nt < 4; ++nt) {
            const int R = wc + nt * 16 + l15;
            #pragma unroll
            for (int s = 0; s < 2; ++s) {
                const int pos = (s * 4 + quad) ^ (R & 7);
                bf[nt][s] = *(const bf16x8*)(const void*)&Bs[R * 64 + pos * 8];
            }
        }
        #pragma unroll
        for (int s = 0; s < 2; ++s)
            #pragma unroll
            for (int mt = 0; mt < 4; ++mt)
                #pragma unroll
                for (int nt = 0; nt < 4; ++nt) {
                    if (OUT_T == 0)
                        acc[mt][nt] = __builtin_amdgcn_mfma_f32_16x16x32_bf16(af[mt][s], bf[nt][s], acc[mt][nt], 0, 0, 0);
                    else
                        acc[mt][nt] = __builtin_amdgcn_mfma_f32_16x16x32_bf16(bf[nt][s], af[mt][s], acc[mt][nt], 0, 0, 0);
                }
        __syncthreads();
    }

    #pragma unroll
    for (int mt = 0; mt < 4; ++mt) {
        #pragma unroll
        for (int nt = 0; nt < 4; ++nt) {
            #pragma unroll
            for (int rg = 0; rg < 4; ++rg) {
                if (OUT_T == 0) {
                    const int col = w0 + wc + nt * 16 + l15;
                    const int row = o0 + wr + mt * 16 + quad * 4 + rg;
                    Pn[(long)row * W_ + col] = (__bf16)(acc[mt][nt][rg] + bias[row]);
                } else {
                    const int o = o0 + wr + mt * 16 + l15;
                    const int w = w0 + wc + nt * 16 + quad * 4 + rg;
                    Pn[(long)w * C_ + o] = (__bf16)(acc[mt][nt][rg] + bias[o]);
                }
            }
        }
    }
}

// ---------------------------------------------------------------------------
// merged Q/K/V GEMM. 1D grid of 1536 blocks, 256 threads. (unchanged)
// ---------------------------------------------------------------------------
__global__ __launch_bounds__(256)
void gemm_qkv(const __bf16* __restrict__ Wb, const __bf16* __restrict__ Xt,
              const float* __restrict__ bq, const float* __restrict__ bk,
              const float* __restrict__ bv,
              __bf16* __restrict__ Qt, __bf16* __restrict__ Kt,
              __bf16* __restrict__ Vb) {
    __shared__ __align__(16) __bf16 As[128 * 64];
    __shared__ __align__(16) __bf16 Bs[128 * 64];
    const int f = blockIdx.x;
    const int n = f & 7;              // XCD = n
    const int j = f >> 3;             // [0,192)
    const int which = j >> 6;         // 0=Q 1=K 2=V
    const int t = j & 63;
    const int o0 = (t >> 3) * 128;
    const int w0 = (t & 7) * 128;
    const size_t SZ = (size_t)C_ * W_;
    const size_t WSZ = (size_t)C_ * C_;
    const __bf16* Xn = Xt + (size_t)n * SZ;
    const __bf16* Aw = Wb + (size_t)which * WSZ;
    if (which < 2)
        gemm_body<1>(Aw, Xn, which ? bk : bq, (which ? Kt : Qt) + n * SZ, o0, w0, As, Bs);
    else
        gemm_body<0>(Aw, Xn, bv, Vb + n * SZ, o0, w0, As, Bs);
}

// ---------------------------------------------------------------------------
// MFMA flash attention v3: BARRIER-FREE, register K/V from L2.
// R2 post-mortem: two rounds pinned at 93us with idle pipes (all per-pipe
// work sums ~5x smaller than dur) -> latency-bound on the 4-wave barrier
// convoy, not on VALU/LDS throughput. FETCH=24.8MB shows K/V is L2-hot via
// the XCD group swizzle, so the LDS staging (and its vmcnt(0)+2 barriers
// per iter) is pure serialization. This version:
//  - K/V frags loaded per-wave straight to registers (L1 dedups the 4
//    identical wave streams within a block; L2 holds the group's 256KB).
//  - NO __syncthreads in the kernel: Pl is wave-private (2KB per qs, both
//    qs staged -> bk dead before bv live, keeps VGPR<=128 for 4 waves/SIMD).
//  - __launch_bounds__(256,4) pins the allocator to 128 VGPR.
//  - raw v_exp_f32 via __builtin_amdgcn_exp2f (inputs bounded, no OCML
//    denorm fixup path).
//  - s_setprio(1) around MFMA clusters (waves now phase-diverse: the
//    m191-positive regime).
// ---------------------------------------------------------------------------
__global__ __launch_bounds__(256, 4)
void flash_attn(const __bf16* __restrict__ Qt,
                const __bf16* __restrict__ Kt,
                const __bf16* __restrict__ V,
                const float* __restrict__ mask,
                float* __restrict__ out) {
    __shared__ __align__(16) __bf16 Pl[4 * 2 * 16 * 64];   // 16KB: wave x qs x 2KB

    // f = (g&7) + 8*(m + 8*(g>>3)) : bijective, all members m of group g
    // share f%8 (same XCD), consecutive slots (co-resident in time).
    const int f = blockIdx.x;
    const int g = (f & 7) + ((f >> 6) << 3);   // group = (n,h), 128 groups
    const int m = (f >> 3) & 7;                // q-tile member
    const int n = g >> 4, h = g & 15;
    const int q0 = m * 128;

    const int tid = threadIdx.x;
    const int wave = tid >> 6, lane = tid & 63;
    const int l15 = lane & 15, quad = lane >> 4;
    const long nqk = (long)n * W_ * C_;
    const long nv = (long)n * C_ * W_;
    const int hD = h * D_;
    const float* mrow = mask + (long)n * W_;
    constexpr float SC = 0.125f * 1.44269504f;   // (1/sqrt(D)) * log2(e)
    constexpr float L2E = 1.44269504f;

    char* plb = (char*)Pl + wave * 4096;
    const int swz = (l15 & 7) << 4;
    const int plrow = l15 * 128;

    // per-lane K/V base pointers; loop adds uniform kt offsets.
    const __bf16* kp = Kt + nqk + (long)l15 * C_ + hD + quad * 8;
    const __bf16* vp = V + nv + (long)(hD + l15) * W_ + quad * 8;

    bf16x8 aq[2][2];
    #pragma unroll
    for (int qs = 0; qs < 2; ++qs)
        #pragma unroll
        for (int dc = 0; dc < 2; ++dc)
            aq[qs][dc] = *(const bf16x8*)(const void*)
                (Qt + nqk + (long)(q0 + wave * 32 + qs * 16 + l15) * C_ + hD + dc * 32 + quad * 8);

    f32x4 o_acc[2][4] = {};
    float l_ln[2] = {};   // per-lane partial row sum for q = l15 (per qs)

    #pragma unroll 1
    for (int ti = 0; ti < W_ / 64; ++ti) {
        const int kt = ti * 64;

        // ---- phase 1: K frags -> registers; QK^T + softmax + pack, both qs
        bf16x8 bk[4][2];
        #pragma unroll
        for (int ks = 0; ks < 4; ++ks)
            #pragma unroll
            for (int dc = 0; dc < 2; ++dc)
                bk[ks][dc] = *(const bf16x8*)(const void*)
                    (kp + (long)(kt + ks * 16) * C_ + dc * 32);
        f32x4 mk2[4];
        #pragma unroll
        for (int ks = 0; ks < 4; ++ks) {
            f32x4 mv = *(const f32x4*)(const void*)(mrow + kt + ks * 16 + quad * 4);
            #pragma unroll
            for (int rg = 0; rg < 4; ++rg) mk2[ks][rg] = mv[rg] * L2E;
        }

        #pragma unroll
        for (int qs = 0; qs < 2; ++qs) {
            // swapped QK^T: S^T[k][q]; C/D: col=l15 -> q, row=quad*4+rg -> k
            f32x4 s[4] = {};
            __builtin_amdgcn_s_setprio(1);
            #pragma unroll
            for (int ks = 0; ks < 4; ++ks)
                #pragma unroll
                for (int dc = 0; dc < 2; ++dc)
                    s[ks] = __builtin_amdgcn_mfma_f32_16x16x32_bf16(bk[ks][dc], aq[qs][dc], s[ks], 0, 0, 0);
            __builtin_amdgcn_s_setprio(0);
            // p = exp2(s*SC + mask[k]*log2e); per-lane row-sum (q = l15)
            #pragma unroll
            for (int ks = 0; ks < 4; ++ks) {
                #pragma unroll
                for (int rg = 0; rg < 4; ++rg)
                    s[ks][rg] = __builtin_amdgcn_exp2f(s[ks][rg] * SC + mk2[ks][rg]);
                l_ln[qs] += (s[ks][0] + s[ks][1]) + (s[ks][2] + s[ks][3]);
            }
            // pack P -> wave-private LDS: 4 consecutive k per lane -> one b64
            #pragma unroll
            for (int ks = 0; ks < 4; ++ks) {
                bf16x4 p4;
                #pragma unroll
                for (int rg = 0; rg < 4; ++rg) p4[rg] = (__bf16)s[ks][rg];
                *(bf16x4*)(void*)(plb + qs * 2048 + plrow + ((ks * 32 + quad * 8) ^ swz)) = p4;
            }
        }

        // ---- phase 2: V frags -> registers (bk dead, regs reuse); PV both qs
        bf16x8 bv[4][2];
        #pragma unroll
        for (int ds = 0; ds < 4; ++ds)
            #pragma unroll
            for (int kc = 0; kc < 2; ++kc)
                bv[ds][kc] = *(const bf16x8*)(const void*)
                    (vp + (long)(ds * 16) * W_ + kt + kc * 32);

        #pragma unroll
        for (int qs = 0; qs < 2; ++qs) {
            bf16x8 ap[2];
            #pragma unroll
            for (int kc = 0; kc < 2; ++kc)
                ap[kc] = *(const bf16x8*)(const void*)
                    (plb + qs * 2048 + plrow + ((kc * 64 + quad * 16) ^ swz));
            __builtin_amdgcn_s_setprio(1);
            #pragma unroll
            for (int ds = 0; ds < 4; ++ds)
                #pragma unroll
                for (int kc = 0; kc < 2; ++kc)
                    o_acc[qs][ds] = __builtin_amdgcn_mfma_f32_16x16x32_bf16(ap[kc], bv[ds][kc], o_acc[qs][ds], 0, 0, 0);
            __builtin_amdgcn_s_setprio(0);
        }
    }

    // final row-sum reduce: partials live at lanes sharing l15 (4 quads)
    #pragma unroll
    for (int qs = 0; qs < 2; ++qs) {
        float l = l_ln[qs];
        l += __shfl_xor(l, 16, 64);
        l += __shfl_xor(l, 32, 64);
        const float linv = 1.0f / l;   // valid at every lane, for q = l15
        #pragma unroll
        for (int rg = 0; rg < 4; ++rg) {
            const float inv = __shfl(linv, quad * 4 + rg, 64);  // l for q=quad*4+rg
            #pragma unroll
            for (int ds = 0; ds < 4; ++ds)
                out[nv + (long)(hD + ds * 16 + l15) * W_ + q0 + wave * 32 + qs * 16 + quad * 4 + rg]
                    = o_acc[qs][ds][rg] * inv;
        }
    }
}

// ---------------------------------------------------------------------------
extern "C" void kernel_launch(void* const* d_in, const int* in_sizes, int n_in,
                              void* d_out, int out_size, void* d_ws, size_t ws_size,
                              hipStream_t stream) {
    (void)in_sizes; (void)n_in; (void)out_size; (void)ws_size;
    const float* hs   = (const float*)d_in[0];
    const float* mask = (const float*)d_in[1];
    const float* wq   = (const float*)d_in[2];
    const float* bq   = (const float*)d_in[3];
    const float* wk   = (const float*)d_in[4];
    const float* bk   = (const float*)d_in[5];
    const float* wv   = (const float*)d_in[6];
    const float* bv   = (const float*)d_in[7];
    float* out = (float*)d_out;

    const size_t SZ = (size_t)N_ * C_ * W_;
    const size_t WSZ = (size_t)C_ * C_;
    __bf16* Wb = (__bf16*)d_ws;                 // [3][C,C] bf16 weights
    __bf16* Xt = Wb + 3 * WSZ;                  // [n,w,c] bf16
    __bf16* Qt = Xt + SZ;                       // [n,w,c]
    __bf16* Kt = Qt + SZ;                       // [n,w,c]
    __bf16* Vb = Kt + SZ;                       // [n,c,w]

    convert_w<<<dim3(512, 3), 256, 0, stream>>>(wq, wk, wv, Wb);
    transpose_x<<<dim3(W_ / 64, C_ / 64, N_), 256, 0, stream>>>(hs, Xt);

    gemm_qkv<<<dim3(1536), 256, 0, stream>>>(Wb, Xt, bq, bk, bv, Qt, Kt, Vb);

    flash_attn<<<dim3(1024), 256, 0, stream>>>(Qt, Kt, Vb, mask, out);
}

// Round 4
// 235.541 us; speedup vs baseline: 1.2545x; 1.2545x over previous
//
#include <hip/hip_runtime.h>
#include <hip/hip_bf16.h>

typedef __bf16 bf16x8 __attribute__((ext_vector_type(8)));
typedef __bf16 bf16x4 __attribute__((ext_vector_type(4)));
typedef float f32x4 __attribute__((ext_vector_type(4)));

#define N_ 8
#define C_ 1024
#define W_ 1024
#define H_ 16
#define D_ 64

// async global->LDS, 16B per lane; LDS dest = wave-uniform base + lane*16
typedef __attribute__((address_space(3))) void lds_void;
typedef const __attribute__((address_space(1))) void gbl_void;
static __device__ __forceinline__ void gload_lds16(const void* g, void* l) {
    __builtin_amdgcn_global_load_lds((gbl_void*)g, (lds_void*)l, 16, 0, 0);
}

// ---------------------------------------------------------------------------
// prep: fused {transpose+convert hs} and {convert 3 weight matrices}.
// blocks [0,2048): transpose_x 64x64 tiles; blocks [2048,3584): convert_w.
// ---------------------------------------------------------------------------
__global__ __launch_bounds__(256)
void prep(const float* __restrict__ hs,
          const float* __restrict__ wq, const float* __restrict__ wk,
          const float* __restrict__ wv,
          __bf16* __restrict__ Xt, __bf16* __restrict__ Wb) {
    __shared__ float tile[64][68];
    const int b = blockIdx.x;
    const int t = threadIdx.x;
    if (b < 2048) {
        // ---- transpose+convert hs [n][C][W] fp32 -> Xt [n][W][C] bf16
        const int bx = b & 15, by = (b >> 4) & 15, bz = b >> 8;
        const long bin  = (long)bz * C_ * W_;
        const long bout = (long)bz * W_ * C_;
        const int w0 = bx * 64, c0 = by * 64;
        const int rr = t >> 4;
        const int cg = (t & 15) * 4;
        #pragma unroll
        for (int it = 0; it < 4; ++it) {
            const int cr = it * 16 + rr;
            f32x4 v = *(const f32x4*)(const void*)(hs + bin + (long)(c0 + cr) * W_ + w0 + cg);
            *(f32x4*)&tile[cr][cg] = v;
        }
        __syncthreads();
        #pragma unroll
        for (int it = 0; it < 4; ++it) {
            const int wr = it * 16 + rr;
            bf16x4 o;
            #pragma unroll
            for (int u = 0; u < 4; ++u) o[u] = (__bf16)tile[cg + u][wr];
            *(bf16x4*)(void*)(Xt + bout + (long)(w0 + wr) * C_ + c0 + cg) = o;
        }
    } else {
        // ---- convert one weight matrix slice fp32 -> bf16
        const int cb = b - 2048;
        const int wsel = cb >> 9;           // 0=Q 1=K 2=V (512 blocks each)
        const int x = cb & 511;
        const float* s = wsel == 0 ? wq : (wsel == 1 ? wk : wv);
        __bf16* d = Wb + (long)wsel * C_ * C_;
        const long i = ((long)x * 256 + t) * 8;
        f32x4 a = *(const f32x4*)(const void*)(s + i);
        f32x4 bb = *(const f32x4*)(const void*)(s + i + 4);
        bf16x8 v;
        #pragma unroll
        for (int u = 0; u < 4; ++u) { v[u] = (__bf16)a[u]; v[u + 4] = (__bf16)bb[u]; }
        *(bf16x8*)(void*)(d + i) = v;
    }
}

// ---------------------------------------------------------------------------
// gemm_body<OUT_T> v2: D = A x B^T, K=1024, bf16, BK=32, 2-PHASE double
// buffer (T3-min): STAGE(next buf) issued at top of iter, ds_read + 16 MFMA
// on current buf, vmcnt(0) + ONE barrier at bottom -> stage loads overlap a
// full compute phase (old structure fully drained before compute: 0 overlap).
// LDS 32KB (2 bufs x 8KB x 2 matrices), XOR chunk swizzle (r&3).
// ---------------------------------------------------------------------------
template<int OUT_T>
static __device__ __forceinline__
void gemm_body(const __bf16* __restrict__ Aw, const __bf16* __restrict__ Xn,
               const float* __restrict__ bias, __bf16* __restrict__ Pn,
               const int o0, const int w0,
               __bf16* __restrict__ As, __bf16* __restrict__ Bs) {
    const int tid = threadIdx.x;
    const int wv = tid >> 6, lane = tid & 63;
    const int l15 = lane & 15, quad = lane >> 4;
    const int wr = (wv >> 1) * 64, wc = (wv & 1) * 64;
    const int lr4 = lane >> 2;      // row within 16-row segment
    const int lc4 = lane & 3;       // 16B chunk within 64B row

    f32x4 acc[4][4] = {};

    // stage one 128x32 A-tile + B-tile into buffer b (4 gload_lds per wave)
    auto stage = [&](int k0, int b) {
        #pragma unroll
        for (int j = 0; j < 2; ++j) {
            const int seg = wv * 2 + j;           // 8 segments of 16 rows
            const int r = seg * 16 + lr4;
            const int q = lc4 ^ (r & 3);          // XOR chunk swizzle (involution)
            gload_lds16(Aw + (long)(o0 + r) * C_ + k0 + q * 8, As + b * 4096 + seg * 512);
            gload_lds16(Xn + (long)(w0 + r) * C_ + k0 + q * 8, Bs + b * 4096 + seg * 512);
        }
    };

    stage(0, 0);
    asm volatile("s_waitcnt vmcnt(0)" ::: "memory");
    __syncthreads();

    for (int ti = 0; ti < 32; ++ti) {
        const int cur = ti & 1;
        if (ti + 1 < 32) stage((ti + 1) * 32, cur ^ 1);   // overlaps compute below

        const __bf16* Ab = As + cur * 4096;
        const __bf16* Bb = Bs + cur * 4096;
        bf16x8 af[4], bf[4];
        #pragma unroll
        for (int mt = 0; mt < 4; ++mt) {
            const int R = wr + mt * 16 + l15;
            const int pos = quad ^ (R & 3);
            af[mt] = *(const bf16x8*)(const void*)&Ab[R * 32 + pos * 8];
        }
        #pragma unroll
        for (int nt = 0; nt < 4; ++nt) {
            const int R = wc + nt * 16 + l15;
            const int pos = quad ^ (R & 3);
            bf[nt] = *(const bf16x8*)(const void*)&Bb[R * 32 + pos * 8];
        }
        #pragma unroll
        for (int mt = 0; mt < 4; ++mt)
            #pragma unroll
            for (int nt = 0; nt < 4; ++nt) {
                if (OUT_T == 0)
                    acc[mt][nt] = __builtin_amdgcn_mfma_f32_16x16x32_bf16(af[mt], bf[nt], acc[mt][nt], 0, 0, 0);
                else
                    acc[mt][nt] = __builtin_amdgcn_mfma_f32_16x16x32_bf16(bf[nt], af[mt], acc[mt][nt], 0, 0, 0);
            }
        // drain THIS iter's stage (it had the whole compute above to land),
        // one barrier: next iter may overwrite buf cur^1... wait: next iter
        // stages into buf[cur] (read just now) - barrier guarantees all waves
        // finished reading it.
        asm volatile("s_waitcnt vmcnt(0)" ::: "memory");
        __syncthreads();
    }

    #pragma unroll
    for (int mt = 0; mt < 4; ++mt) {
        #pragma unroll
        for (int nt = 0; nt < 4; ++nt) {
            #pragma unroll
            for (int rg = 0; rg < 4; ++rg) {
                if (OUT_T == 0) {
                    const int col = w0 + wc + nt * 16 + l15;
                    const int row = o0 + wr + mt * 16 + quad * 4 + rg;
                    Pn[(long)row * W_ + col] = (__bf16)(acc[mt][nt][rg] + bias[row]);
                } else {
                    const int o = o0 + wr + mt * 16 + l15;
                    const int w = w0 + wc + nt * 16 + quad * 4 + rg;
                    Pn[(long)w * C_ + o] = (__bf16)(acc[mt][nt][rg] + bias[o]);
                }
            }
        }
    }
}

// ---------------------------------------------------------------------------
// merged Q/K/V GEMM. 1D grid of 1536 blocks, 256 threads.
// XCD swizzle: n = f & 7 -> each XCD owns one batch's Xt slab (L2-resident).
// ---------------------------------------------------------------------------
__global__ __launch_bounds__(256)
void gemm_qkv(const __bf16* __restrict__ Wb, const __bf16* __restrict__ Xt,
              const float* __restrict__ bq, const float* __restrict__ bk,
              const float* __restrict__ bv,
              __bf16* __restrict__ Qt, __bf16* __restrict__ Kt,
              __bf16* __restrict__ Vb) {
    __shared__ __align__(16) __bf16 As[2 * 4096];   // 16KB
    __shared__ __align__(16) __bf16 Bs[2 * 4096];   // 16KB
    const int f = blockIdx.x;
    const int n = f & 7;              // XCD = n
    const int j = f >> 3;             // [0,192)
    const int which = j >> 6;         // 0=Q 1=K 2=V
    const int t = j & 63;
    const int o0 = (t >> 3) * 128;
    const int w0 = (t & 7) * 128;
    const size_t SZ = (size_t)C_ * W_;
    const size_t WSZ = (size_t)C_ * C_;
    const __bf16* Xn = Xt + (size_t)n * SZ;
    const __bf16* Aw = Wb + (size_t)which * WSZ;
    if (which < 2)
        gemm_body<1>(Aw, Xn, which ? bk : bq, (which ? Kt : Qt) + n * SZ, o0, w0, As, Bs);
    else
        gemm_body<0>(Aw, Xn, bv, Vb + n * SZ, o0, w0, As, Bs);
}

// ---------------------------------------------------------------------------
// MFMA flash attention (R2 structure restored; R3's reg-K/V experiment
// regressed: launch_bounds(256,4) => 64 VGPR + scratch spills).
// Fixes/changes vs R2:
//  - Pl bounds bug FIXED: R2 indexed 16KB into an 8KB array (wave3/qs1
//    overflowed into Ks[0]). Now Pl = 2KB/wave, REUSED across qs (pack qs0,
//    read ap0, overwrite with qs1, read ap1 - in-order per-wave DS ops).
//  - Both-qs QK^T computed FIRST (16 independent MFMA chains hide MFMA->exp
//    latency), then softmax both, then pack/ap, then PV both.
//  - LDS = 8 + 16 + 16 = 40KB -> 4 blocks/CU. No launch_bounds min.
// ---------------------------------------------------------------------------
__global__ __launch_bounds__(256)
void flash_attn(const __bf16* __restrict__ Qt,
                const __bf16* __restrict__ Kt,
                const __bf16* __restrict__ V,
                const float* __restrict__ mask,
                float* __restrict__ out) {
    __shared__ __align__(16) __bf16 Pl[4 * 16 * 64];   // 8KB: 2KB/wave, qs-reused
    __shared__ __align__(16) __bf16 Ks[2][64 * 64];    // 16KB
    __shared__ __align__(16) __bf16 Vs[2][64 * 64];    // 16KB -> total 40960

    // f = (g&7) + 8*(m + 8*(g>>3)) : bijective, all members m of group g
    // share f%8 (same XCD), consecutive slots (co-resident in time).
    const int f = blockIdx.x;
    const int g = (f & 7) + ((f >> 6) << 3);   // group = (n,h), 128 groups
    const int m = (f >> 3) & 7;                // q-tile member
    const int n = g >> 4, h = g & 15;
    const int q0 = m * 128;

    const int tid = threadIdx.x;
    const int wave = tid >> 6, lane = tid & 63;
    const int l15 = lane & 15, quad = lane >> 4;
    const int lr8 = lane >> 3, lp = lane & 7;
    const long nqk = (long)n * W_ * C_;
    const long nv = (long)n * C_ * W_;
    const int hD = h * D_;
    const float* mrow = mask + (long)n * W_;
    constexpr float SC = 0.125f * 1.44269504f;   // (1/sqrt(D)) * log2(e)
    constexpr float L2E = 1.44269504f;

    char* plb = (char*)Pl + wave * 2048;
    const int swz = (l15 & 7) << 4;
    const int plrow = l15 * 128;

    bf16x8 aq[2][2];
    #pragma unroll
    for (int qs = 0; qs < 2; ++qs)
        #pragma unroll
        for (int dc = 0; dc < 2; ++dc)
            aq[qs][dc] = *(const bf16x8*)(const void*)
                (Qt + nqk + (long)(q0 + wave * 32 + qs * 16 + l15) * C_ + hD + dc * 32 + quad * 8);

    f32x4 o_acc[2][4] = {};
    float l_ln[2] = {};   // per-lane partial row sum for q = l15 (per qs)

    // stage one 64-row K tile + 64-row V tile into buffer b.
    // XOR chunk swizzle on the GLOBAL source (q = lp ^ (r&7)), LDS linear.
    auto stage = [&](int kt, int b) {
        #pragma unroll
        for (int jj = 0; jj < 2; ++jj) {
            const int seg = wave * 2 + jj;
            const int r = seg * 8 + lr8;
            const int q = lp ^ (r & 7);
            gload_lds16(Kt + nqk + (long)(kt + r) * C_ + hD + q * 8, &Ks[b][seg * 512]);
            gload_lds16(V + nv + (long)(hD + r) * W_ + kt + q * 8, &Vs[b][seg * 512]);
        }
    };

    stage(0, 0);

    for (int ti = 0; ti < W_ / 64; ++ti) {
        const int kt = ti * 64;
        const int cur = ti & 1;
        // current buffer's stage (issued last iter / prologue) must land;
        // barrier also fences: all waves done READING buf cur^1 before the
        // stage below overwrites it.
        asm volatile("s_waitcnt vmcnt(0)" ::: "memory");
        __syncthreads();
        if (ti + 1 < W_ / 64) stage(kt + 64, cur ^ 1);

        // K frags from LDS (swizzled chunk position, 2-way = free)
        bf16x8 bk[4][2];
        #pragma unroll
        for (int ks = 0; ks < 4; ++ks)
            #pragma unroll
            for (int dc = 0; dc < 2; ++dc) {
                const int R = ks * 16 + l15;
                const int pos = (dc * 4 + quad) ^ (R & 7);
                bk[ks][dc] = *(const bf16x8*)(const void*)&Ks[cur][R * 64 + pos * 8];
            }
        // mask for this tile's k rows: k = kt + ks*16 + quad*4 + rg
        f32x4 mk2[4];
        #pragma unroll
        for (int ks = 0; ks < 4; ++ks) {
            f32x4 mv = *(const f32x4*)(const void*)(mrow + kt + ks * 16 + quad * 4);
            #pragma unroll
            for (int rg = 0; rg < 4; ++rg) mk2[ks][rg] = mv[rg] * L2E;
        }

        // ---- QK^T for BOTH qs first: 16 independent MFMA chains
        // swapped operands: S^T[k][q]; C/D: col=l15 -> q, row=quad*4+rg -> k
        f32x4 s2[2][4] = {};
        #pragma unroll
        for (int qs = 0; qs < 2; ++qs)
            #pragma unroll
            for (int ks = 0; ks < 4; ++ks)
                #pragma unroll
                for (int dc = 0; dc < 2; ++dc)
                    s2[qs][ks] = __builtin_amdgcn_mfma_f32_16x16x32_bf16(bk[ks][dc], aq[qs][dc], s2[qs][ks], 0, 0, 0);

        // ---- softmax both qs: p = exp2(s*SC + mask[k]*log2e), row sums
        #pragma unroll
        for (int qs = 0; qs < 2; ++qs)
            #pragma unroll
            for (int ks = 0; ks < 4; ++ks) {
                #pragma unroll
                for (int rg = 0; rg < 4; ++rg)
                    s2[qs][ks][rg] = __builtin_amdgcn_exp2f(s2[qs][ks][rg] * SC + mk2[ks][rg]);
                l_ln[qs] += (s2[qs][ks][0] + s2[qs][ks][1]) + (s2[qs][ks][2] + s2[qs][ks][3]);
            }

        // ---- pack P -> wave-private LDS (2KB reused), read back as A-frags
        bf16x8 ap[2][2];
        #pragma unroll
        for (int qs = 0; qs < 2; ++qs) {
            #pragma unroll
            for (int ks = 0; ks < 4; ++ks) {
                bf16x4 p4;
                #pragma unroll
                for (int rg = 0; rg < 4; ++rg) p4[rg] = (__bf16)s2[qs][ks][rg];
                *(bf16x4*)(void*)(plb + plrow + ((ks * 32 + quad * 8) ^ swz)) = p4;
            }
            #pragma unroll
            for (int kc = 0; kc < 2; ++kc)
                ap[qs][kc] = *(const bf16x8*)(const void*)
                    (plb + plrow + ((kc * 64 + quad * 16) ^ swz));
        }

        // ---- V frags + PV both qs
        bf16x8 bv[4][2];
        #pragma unroll
        for (int ds = 0; ds < 4; ++ds)
            #pragma unroll
            for (int kc = 0; kc < 2; ++kc) {
                const int R = ds * 16 + l15;
                const int pos = (kc * 4 + quad) ^ (R & 7);
                bv[ds][kc] = *(const bf16x8*)(const void*)&Vs[cur][R * 64 + pos * 8];
            }
        #pragma unroll
        for (int qs = 0; qs < 2; ++qs)
            #pragma unroll
            for (int ds = 0; ds < 4; ++ds)
                #pragma unroll
                for (int kc = 0; kc < 2; ++kc)
                    o_acc[qs][ds] = __builtin_amdgcn_mfma_f32_16x16x32_bf16(ap[qs][kc], bv[ds][kc], o_acc[qs][ds], 0, 0, 0);
    }

    // final row-sum reduce: partials live at lanes sharing l15 (4 quads)
    #pragma unroll
    for (int qs = 0; qs < 2; ++qs) {
        float l = l_ln[qs];
        l += __shfl_xor(l, 16, 64);
        l += __shfl_xor(l, 32, 64);
        const float linv = 1.0f / l;   // valid at every lane, for q = l15
        #pragma unroll
        for (int rg = 0; rg < 4; ++rg) {
            const float inv = __shfl(linv, quad * 4 + rg, 64);  // l for q=quad*4+rg
            #pragma unroll
            for (int ds = 0; ds < 4; ++ds)
                out[nv + (long)(hD + ds * 16 + l15) * W_ + q0 + wave * 32 + qs * 16 + quad * 4 + rg]
                    = o_acc[qs][ds][rg] * inv;
        }
    }
}

// ---------------------------------------------------------------------------
extern "C" void kernel_launch(void* const* d_in, const int* in_sizes, int n_in,
                              void* d_out, int out_size, void* d_ws, size_t ws_size,
                              hipStream_t stream) {
    (void)in_sizes; (void)n_in; (void)out_size; (void)ws_size;
    const float* hs   = (const float*)d_in[0];
    const float* mask = (const float*)d_in[1];
    const float* wq   = (const float*)d_in[2];
    const float* bq   = (const float*)d_in[3];
    const float* wk   = (const float*)d_in[4];
    const float* bk   = (const float*)d_in[5];
    const float* wv   = (const float*)d_in[6];
    const float* bv   = (const float*)d_in[7];
    float* out = (float*)d_out;

    const size_t SZ = (size_t)N_ * C_ * W_;
    const size_t WSZ = (size_t)C_ * C_;
    __bf16* Wb = (__bf16*)d_ws;                 // [3][C,C] bf16 weights
    __bf16* Xt = Wb + 3 * WSZ;                  // [n,w,c] bf16
    __bf16* Qt = Xt + SZ;                       // [n,w,c]
    __bf16* Kt = Qt + SZ;                       // [n,w,c]
    __bf16* Vb = Kt + SZ;                       // [n,c,w]

    prep<<<dim3(2048 + 1536), 256, 0, stream>>>(hs, wq, wk, wv, Xt, Wb);

    gemm_qkv<<<dim3(1536), 256, 0, stream>>>(Wb, Xt, bq, bk, bv, Qt, Kt, Vb);

    flash_attn<<<dim3(1024), 256, 0, stream>>>(Qt, Kt, Vb, mask, out);
}

// Round 6
// 232.629 us; speedup vs baseline: 1.2702x; 1.0125x over previous
//
#include <hip/hip_runtime.h>
#include <hip/hip_bf16.h>

typedef __bf16 bf16x8 __attribute__((ext_vector_type(8)));
typedef __bf16 bf16x4 __attribute__((ext_vector_type(4)));
typedef float f32x4 __attribute__((ext_vector_type(4)));

#define N_ 8
#define C_ 1024
#define W_ 1024
#define H_ 16
#define D_ 64

// async global->LDS, 16B per lane; LDS dest = wave-uniform base + lane*16
typedef __attribute__((address_space(3))) void lds_void;
typedef const __attribute__((address_space(1))) void gbl_void;
static __device__ __forceinline__ void gload_lds16(const void* g, void* l) {
    __builtin_amdgcn_global_load_lds((gbl_void*)g, (lds_void*)l, 16, 0, 0);
}

// ---------------------------------------------------------------------------
// prep: fused {transpose+convert hs} and {convert 3 weight matrices}.
// blocks [0,2048): transpose_x 64x64 tiles; blocks [2048,3584): convert_w.
// ---------------------------------------------------------------------------
__global__ __launch_bounds__(256)
void prep(const float* __restrict__ hs,
          const float* __restrict__ wq, const float* __restrict__ wk,
          const float* __restrict__ wv,
          __bf16* __restrict__ Xt, __bf16* __restrict__ Wb) {
    __shared__ float tile[64][68];
    const int b = blockIdx.x;
    const int t = threadIdx.x;
    if (b < 2048) {
        // ---- transpose+convert hs [n][C][W] fp32 -> Xt [n][W][C] bf16
        const int bx = b & 15, by = (b >> 4) & 15, bz = b >> 8;
        const long bin  = (long)bz * C_ * W_;
        const long bout = (long)bz * W_ * C_;
        const int w0 = bx * 64, c0 = by * 64;
        const int rr = t >> 4;
        const int cg = (t & 15) * 4;
        #pragma unroll
        for (int it = 0; it < 4; ++it) {
            const int cr = it * 16 + rr;
            f32x4 v = *(const f32x4*)(const void*)(hs + bin + (long)(c0 + cr) * W_ + w0 + cg);
            *(f32x4*)&tile[cr][cg] = v;
        }
        __syncthreads();
        #pragma unroll
        for (int it = 0; it < 4; ++it) {
            const int wr = it * 16 + rr;
            bf16x4 o;
            #pragma unroll
            for (int u = 0; u < 4; ++u) o[u] = (__bf16)tile[cg + u][wr];
            *(bf16x4*)(void*)(Xt + bout + (long)(w0 + wr) * C_ + c0 + cg) = o;
        }
    } else {
        // ---- convert one weight matrix slice fp32 -> bf16
        const int cb = b - 2048;
        const int wsel = cb >> 9;           // 0=Q 1=K 2=V (512 blocks each)
        const int x = cb & 511;
        const float* s = wsel == 0 ? wq : (wsel == 1 ? wk : wv);
        __bf16* d = Wb + (long)wsel * C_ * C_;
        const long i = ((long)x * 256 + t) * 8;
        f32x4 a = *(const f32x4*)(const void*)(s + i);
        f32x4 bb = *(const f32x4*)(const void*)(s + i + 4);
        bf16x8 v;
        #pragma unroll
        for (int u = 0; u < 4; ++u) { v[u] = (__bf16)a[u]; v[u + 4] = (__bf16)bb[u]; }
        *(bf16x8*)(void*)(d + i) = v;
    }
}

// ---------------------------------------------------------------------------
// gemm_body<OUT_T> v4: D = A x B^T, K=1024, bf16, BK=32.
// R5 bug fixes:
//  - stage-buffer rotation via explicit nxt counter (R5's conditional
//    returned buf0 instead of buf1 at cur==2 -> clobbered live tile).
//  - raw s_barrier instead of __syncthreads (whose semantics force a
//    vmcnt(0) drain before s_barrier, nullifying the counted vmcnt(4)).
//    asm "memory" fences on both sides pin gload_lds/ds_read ordering.
// Pipeline: prologue stages tile0->buf0, tile1->buf1. Iter t: vmcnt(4)
// [own oldest stage landed, newest still flying] -> barrier [all waves'
// current-buf stages landed; all reads of buf staged next are done] ->
// stage tile t+2 -> compute buf[t%3]. Stage gets ~2 compute phases of
// latency cover; queue never drains to 0 except the peeled last iter.
// Swizzle sigma(R)=(R>>1)&3: slot%8 = 4*(R&1) + quad^sigma covers all 8
// chunk-slots uniformly (R4's R&3 version collapsed to 4 -> 6.3M conflicts).
// LDS 48KB (3 bufs x 8KB x 2 matrices) -> 3 blocks/CU.
// ---------------------------------------------------------------------------
template<int OUT_T>
static __device__ __forceinline__
void gemm_body(const __bf16* __restrict__ Aw, const __bf16* __restrict__ Xn,
               const float* __restrict__ bias, __bf16* __restrict__ Pn,
               const int o0, const int w0,
               __bf16* __restrict__ As, __bf16* __restrict__ Bs) {
    const int tid = threadIdx.x;
    const int wv = tid >> 6, lane = tid & 63;
    const int l15 = lane & 15, quad = lane >> 4;
    const int wr = (wv >> 1) * 64, wc = (wv & 1) * 64;
    const int lr4 = lane >> 2;      // row within 16-row segment
    const int lc4 = lane & 3;       // 16B chunk within 64B row

    f32x4 acc[4][4] = {};

    // stage one 128x32 A-tile + B-tile into buffer b (4 gload_lds per wave).
    // XOR chunk swizzle on the GLOBAL source: q = lc4 ^ ((row>>1)&3); LDS
    // stays lane-linear (gload_lds requirement).
    auto stage = [&](int k0, int b) {
        #pragma unroll
        for (int j = 0; j < 2; ++j) {
            const int seg = wv * 2 + j;           // 8 segments of 16 rows
            const int r = seg * 16 + lr4;
            const int q = lc4 ^ ((lr4 >> 1) & 3);
            gload_lds16(Aw + (long)(o0 + r) * C_ + k0 + q * 8, As + b * 4096 + seg * 512);
            gload_lds16(Xn + (long)(w0 + r) * C_ + k0 + q * 8, Bs + b * 4096 + seg * 512);
        }
    };

    stage(0, 0);
    stage(32, 1);

    int cur = 0, nxt = 2;
    #pragma unroll 1
    for (int ti = 0; ti < 32; ++ti) {
        // own stage for buf[cur] is the oldest outstanding; newest stage
        // (4 ops) stays in flight. Last iter: nothing newer -> full drain.
        if (ti < 31) asm volatile("s_waitcnt vmcnt(4)" ::: "memory");
        else         asm volatile("s_waitcnt vmcnt(0)" ::: "memory");
        __builtin_amdgcn_s_barrier();
        asm volatile("" ::: "memory");
        // buf[nxt] was last READ at iter ti-1; the barrier above fences
        // those reads, so overwriting it now is safe.
        if (ti + 2 < 32) {
            stage((ti + 2) * 32, nxt);
            nxt = nxt + 1 == 3 ? 0 : nxt + 1;
        }

        const __bf16* Ab = As + cur * 4096;
        const __bf16* Bb = Bs + cur * 4096;
        bf16x8 af[4], bf[4];
        #pragma unroll
        for (int mt = 0; mt < 4; ++mt) {
            const int R = wr + mt * 16 + l15;
            const int pos = quad ^ ((R >> 1) & 3);
            af[mt] = *(const bf16x8*)(const void*)&Ab[R * 32 + pos * 8];
        }
        #pragma unroll
        for (int nt = 0; nt < 4; ++nt) {
            const int R = wc + nt * 16 + l15;
            const int pos = quad ^ ((R >> 1) & 3);
            bf[nt] = *(const bf16x8*)(const void*)&Bb[R * 32 + pos * 8];
        }
        #pragma unroll
        for (int mt = 0; mt < 4; ++mt)
            #pragma unroll
            for (int nt = 0; nt < 4; ++nt) {
                if (OUT_T == 0)
                    acc[mt][nt] = __builtin_amdgcn_mfma_f32_16x16x32_bf16(af[mt], bf[nt], acc[mt][nt], 0, 0, 0);
                else
                    acc[mt][nt] = __builtin_amdgcn_mfma_f32_16x16x32_bf16(bf[nt], af[mt], acc[mt][nt], 0, 0, 0);
            }
        cur = cur + 1 == 3 ? 0 : cur + 1;
    }

    #pragma unroll
    for (int mt = 0; mt < 4; ++mt) {
        #pragma unroll
        for (int nt = 0; nt < 4; ++nt) {
            #pragma unroll
            for (int rg = 0; rg < 4; ++rg) {
                if (OUT_T == 0) {
                    const int col = w0 + wc + nt * 16 + l15;
                    const int row = o0 + wr + mt * 16 + quad * 4 + rg;
                    Pn[(long)row * W_ + col] = (__bf16)(acc[mt][nt][rg] + bias[row]);
                } else {
                    const int o = o0 + wr + mt * 16 + l15;
                    const int w = w0 + wc + nt * 16 + quad * 4 + rg;
                    Pn[(long)w * C_ + o] = (__bf16)(acc[mt][nt][rg] + bias[o]);
                }
            }
        }
    }
}

// ---------------------------------------------------------------------------
// merged Q/K/V GEMM. 1D grid of 1536 blocks, 256 threads.
// XCD swizzle: n = f & 7 -> each XCD owns one batch's Xt slab (L2-resident).
// ---------------------------------------------------------------------------
__global__ __launch_bounds__(256)
void gemm_qkv(const __bf16* __restrict__ Wb, const __bf16* __restrict__ Xt,
              const float* __restrict__ bq, const float* __restrict__ bk,
              const float* __restrict__ bv,
              __bf16* __restrict__ Qt, __bf16* __restrict__ Kt,
              __bf16* __restrict__ Vb) {
    __shared__ __align__(16) __bf16 As[3 * 4096];   // 24KB
    __shared__ __align__(16) __bf16 Bs[3 * 4096];   // 24KB
    const int f = blockIdx.x;
    const int n = f & 7;              // XCD = n
    const int j = f >> 3;             // [0,192)
    const int which = j >> 6;         // 0=Q 1=K 2=V
    const int t = j & 63;
    const int o0 = (t >> 3) * 128;
    const int w0 = (t & 7) * 128;
    const size_t SZ = (size_t)C_ * W_;
    const size_t WSZ = (size_t)C_ * C_;
    const __bf16* Xn = Xt + (size_t)n * SZ;
    const __bf16* Aw = Wb + (size_t)which * WSZ;
    if (which < 2)
        gemm_body<1>(Aw, Xn, which ? bk : bq, (which ? Kt : Qt) + n * SZ, o0, w0, As, Bs);
    else
        gemm_body<0>(Aw, Xn, bv, Vb + n * SZ, o0, w0, As, Bs);
}

// ---------------------------------------------------------------------------
// MFMA flash attention (unchanged from R4: R2 structure, Pl bug fixed,
// both-qs QK^T first; measured < 84us, no longer the top kernel).
// ---------------------------------------------------------------------------
__global__ __launch_bounds__(256)
void flash_attn(const __bf16* __restrict__ Qt,
                const __bf16* __restrict__ Kt,
                const __bf16* __restrict__ V,
                const float* __restrict__ mask,
                float* __restrict__ out) {
    __shared__ __align__(16) __bf16 Pl[4 * 16 * 64];   // 8KB: 2KB/wave, qs-reused
    __shared__ __align__(16) __bf16 Ks[2][64 * 64];    // 16KB
    __shared__ __align__(16) __bf16 Vs[2][64 * 64];    // 16KB -> total 40960

    // f = (g&7) + 8*(m + 8*(g>>3)) : bijective, all members m of group g
    // share f%8 (same XCD), consecutive slots (co-resident in time).
    const int f = blockIdx.x;
    const int g = (f & 7) + ((f >> 6) << 3);   // group = (n,h), 128 groups
    const int m = (f >> 3) & 7;                // q-tile member
    const int n = g >> 4, h = g & 15;
    const int q0 = m * 128;

    const int tid = threadIdx.x;
    const int wave = tid >> 6, lane = tid & 63;
    const int l15 = lane & 15, quad = lane >> 4;
    const int lr8 = lane >> 3, lp = lane & 7;
    const long nqk = (long)n * W_ * C_;
    const long nv = (long)n * C_ * W_;
    const int hD = h * D_;
    const float* mrow = mask + (long)n * W_;
    constexpr float SC = 0.125f * 1.44269504f;   // (1/sqrt(D)) * log2(e)
    constexpr float L2E = 1.44269504f;

    char* plb = (char*)Pl + wave * 2048;
    const int swz = (l15 & 7) << 4;
    const int plrow = l15 * 128;

    bf16x8 aq[2][2];
    #pragma unroll
    for (int qs = 0; qs < 2; ++qs)
        #pragma unroll
        for (int dc = 0; dc < 2; ++dc)
            aq[qs][dc] = *(const bf16x8*)(const void*)
                (Qt + nqk + (long)(q0 + wave * 32 + qs * 16 + l15) * C_ + hD + dc * 32 + quad * 8);

    f32x4 o_acc[2][4] = {};
    float l_ln[2] = {};   // per-lane partial row sum for q = l15 (per qs)

    // stage one 64-row K tile + 64-row V tile into buffer b.
    // XOR chunk swizzle on the GLOBAL source (q = lp ^ (r&7)), LDS linear.
    auto stage = [&](int kt, int b) {
        #pragma unroll
        for (int jj = 0; jj < 2; ++jj) {
            const int seg = wave * 2 + jj;
            const int r = seg * 8 + lr8;
            const int q = lp ^ (r & 7);
            gload_lds16(Kt + nqk + (long)(kt + r) * C_ + hD + q * 8, &Ks[b][seg * 512]);
            gload_lds16(V + nv + (long)(hD + r) * W_ + kt + q * 8, &Vs[b][seg * 512]);
        }
    };

    stage(0, 0);

    for (int ti = 0; ti < W_ / 64; ++ti) {
        const int kt = ti * 64;
        const int cur = ti & 1;
        // current buffer's stage (issued last iter / prologue) must land;
        // barrier also fences: all waves done READING buf cur^1 before the
        // stage below overwrites it.
        asm volatile("s_waitcnt vmcnt(0)" ::: "memory");
        __syncthreads();
        if (ti + 1 < W_ / 64) stage(kt + 64, cur ^ 1);

        // K frags from LDS (swizzled chunk position, 2-way = free)
        bf16x8 bk[4][2];
        #pragma unroll
        for (int ks = 0; ks < 4; ++ks)
            #pragma unroll
            for (int dc = 0; dc < 2; ++dc) {
                const int R = ks * 16 + l15;
                const int pos = (dc * 4 + quad) ^ (R & 7);
                bk[ks][dc] = *(const bf16x8*)(const void*)&Ks[cur][R * 64 + pos * 8];
            }
        // mask for this tile's k rows: k = kt + ks*16 + quad*4 + rg
        f32x4 mk2[4];
        #pragma unroll
        for (int ks = 0; ks < 4; ++ks) {
            f32x4 mv = *(const f32x4*)(const void*)(mrow + kt + ks * 16 + quad * 4);
            #pragma unroll
            for (int rg = 0; rg < 4; ++rg) mk2[ks][rg] = mv[rg] * L2E;
        }

        // ---- QK^T for BOTH qs first: 16 independent MFMA chains
        // swapped operands: S^T[k][q]; C/D: col=l15 -> q, row=quad*4+rg -> k
        f32x4 s2[2][4] = {};
        #pragma unroll
        for (int qs = 0; qs < 2; ++qs)
            #pragma unroll
            for (int ks = 0; ks < 4; ++ks)
                #pragma unroll
                for (int dc = 0; dc < 2; ++dc)
                    s2[qs][ks] = __builtin_amdgcn_mfma_f32_16x16x32_bf16(bk[ks][dc], aq[qs][dc], s2[qs][ks], 0, 0, 0);

        // ---- softmax both qs: p = exp2(s*SC + mask[k]*log2e), row sums
        #pragma unroll
        for (int qs = 0; qs < 2; ++qs)
            #pragma unroll
            for (int ks = 0; ks < 4; ++ks) {
                #pragma unroll
                for (int rg = 0; rg < 4; ++rg)
                    s2[qs][ks][rg] = __builtin_amdgcn_exp2f(s2[qs][ks][rg] * SC + mk2[ks][rg]);
                l_ln[qs] += (s2[qs][ks][0] + s2[qs][ks][1]) + (s2[qs][ks][2] + s2[qs][ks][3]);
            }

        // ---- pack P -> wave-private LDS (2KB reused), read back as A-frags
        bf16x8 ap[2][2];
        #pragma unroll
        for (int qs = 0; qs < 2; ++qs) {
            #pragma unroll
            for (int ks = 0; ks < 4; ++ks) {
                bf16x4 p4;
                #pragma unroll
                for (int rg = 0; rg < 4; ++rg) p4[rg] = (__bf16)s2[qs][ks][rg];
                *(bf16x4*)(void*)(plb + plrow + ((ks * 32 + quad * 8) ^ swz)) = p4;
            }
            #pragma unroll
            for (int kc = 0; kc < 2; ++kc)
                ap[qs][kc] = *(const bf16x8*)(const void*)
                    (plb + plrow + ((kc * 64 + quad * 16) ^ swz));
        }

        // ---- V frags + PV both qs
        bf16x8 bv[4][2];
        #pragma unroll
        for (int ds = 0; ds < 4; ++ds)
            #pragma unroll
            for (int kc = 0; kc < 2; ++kc) {
                const int R = ds * 16 + l15;
                const int pos = (kc * 4 + quad) ^ (R & 7);
                bv[ds][kc] = *(const bf16x8*)(const void*)&Vs[cur][R * 64 + pos * 8];
            }
        #pragma unroll
        for (int qs = 0; qs < 2; ++qs)
            #pragma unroll
            for (int ds = 0; ds < 4; ++ds)
                #pragma unroll
                for (int kc = 0; kc < 2; ++kc)
                    o_acc[qs][ds] = __builtin_amdgcn_mfma_f32_16x16x32_bf16(ap[qs][kc], bv[ds][kc], o_acc[qs][ds], 0, 0, 0);
    }

    // final row-sum reduce: partials live at lanes sharing l15 (4 quads)
    #pragma unroll
    for (int qs = 0; qs < 2; ++qs) {
        float l = l_ln[qs];
        l += __shfl_xor(l, 16, 64);
        l += __shfl_xor(l, 32, 64);
        const float linv = 1.0f / l;   // valid at every lane, for q = l15
        #pragma unroll
        for (int rg = 0; rg < 4; ++rg) {
            const float inv = __shfl(linv, quad * 4 + rg, 64);  // l for q=quad*4+rg
            #pragma unroll
            for (int ds = 0; ds < 4; ++ds)
                out[nv + (long)(hD + ds * 16 + l15) * W_ + q0 + wave * 32 + qs * 16 + quad * 4 + rg]
                    = o_acc[qs][ds][rg] * inv;
        }
    }
}

// ---------------------------------------------------------------------------
extern "C" void kernel_launch(void* const* d_in, const int* in_sizes, int n_in,
                              void* d_out, int out_size, void* d_ws, size_t ws_size,
                              hipStream_t stream) {
    (void)in_sizes; (void)n_in; (void)out_size; (void)ws_size;
    const float* hs   = (const float*)d_in[0];
    const float* mask = (const float*)d_in[1];
    const float* wq   = (const float*)d_in[2];
    const float* bq   = (const float*)d_in[3];
    const float* wk   = (const float*)d_in[4];
    const float* bk   = (const float*)d_in[5];
    const float* wv   = (const float*)d_in[6];
    const float* bv   = (const float*)d_in[7];
    float* out = (float*)d_out;

    const size_t SZ = (size_t)N_ * C_ * W_;
    const size_t WSZ = (size_t)C_ * C_;
    __bf16* Wb = (__bf16*)d_ws;                 // [3][C,C] bf16 weights
    __bf16* Xt = Wb + 3 * WSZ;                  // [n,w,c] bf16
    __bf16* Qt = Xt + SZ;                       // [n,w,c]
    __bf16* Kt = Qt + SZ;                       // [n,w,c]
    __bf16* Vb = Kt + SZ;                       // [n,c,w]

    prep<<<dim3(2048 + 1536), 256, 0, stream>>>(hs, wq, wk, wv, Xt, Wb);

    gemm_qkv<<<dim3(1536), 256, 0, stream>>>(Wb, Xt, bq, bk, bv, Qt, Kt, Vb);

    flash_attn<<<dim3(1024), 256, 0, stream>>>(Qt, Kt, Vb, mask, out);
}